// Round 2
// baseline (1798.949 us; speedup 1.0000x reference)
//
#include <hip/hip_runtime.h>
#include <cstdint>
#include <cstddef>

// Problem dims (fixed)
// T=10 B=4 C=256 H=W=16 N=256 HEADS=16 d=16 HID=1024 UC=40 STEP=10 R=4
#define EPSF 1e-5f

// ---------------------------------------------------------------------------
// Generic fp32 tiled GEMM with fused bias + batchnorm epilogue.
// Out[slice][o][n] = bn( sum_k W[o][k] * X[slice][k][n] + bias[o] )
// Grid: x = (O/64)*(N/64), y = slices. Block 256.
// ---------------------------------------------------------------------------
__global__ __launch_bounds__(256) void gemm_bn(
    const float* __restrict__ W, const float* __restrict__ X,
    float* __restrict__ Out, const float* __restrict__ bnp,
    const float* __restrict__ bias, int O, int K, int N)
{
    __shared__ float As[16][68];   // [k][o], padded rows (16B-aligned)
    __shared__ float Bs[16][68];   // [k][n]
    const int slice  = blockIdx.y;
    const int tilesn = N >> 6;
    const int to = (blockIdx.x / tilesn) << 6;
    const int tn = (blockIdx.x % tilesn) << 6;
    const float* Xs = X + (size_t)slice * K * N;
    const int tid = threadIdx.x;
    const int tx = tid & 15, ty = tid >> 4;
    const int ol = tid >> 2, kl = (tid & 3) << 2;     // W-tile load coords
    const int krow = tid >> 4, ncol = (tid & 15) << 2; // X-tile load coords

    float acc[4][4];
#pragma unroll
    for (int i = 0; i < 4; ++i)
#pragma unroll
        for (int j = 0; j < 4; ++j) acc[i][j] = 0.0f;

    for (int k0 = 0; k0 < K; k0 += 16) {
        float4 wv = *(const float4*)&W[(size_t)(to + ol) * K + k0 + kl];
        float4 xv = *(const float4*)&Xs[(size_t)(k0 + krow) * N + tn + ncol];
        __syncthreads();
        As[kl + 0][ol] = wv.x; As[kl + 1][ol] = wv.y;
        As[kl + 2][ol] = wv.z; As[kl + 3][ol] = wv.w;
        *(float4*)&Bs[krow][ncol] = xv;
        __syncthreads();
#pragma unroll
        for (int kk = 0; kk < 16; ++kk) {
            float4 av = *(const float4*)&As[kk][ty << 2];
            float4 bv = *(const float4*)&Bs[kk][tx << 2];
            float a[4] = {av.x, av.y, av.z, av.w};
            float b[4] = {bv.x, bv.y, bv.z, bv.w};
#pragma unroll
            for (int i = 0; i < 4; ++i)
#pragma unroll
                for (int j = 0; j < 4; ++j)
                    acc[i][j] = fmaf(a[i], b[j], acc[i][j]);
        }
    }
    float* Op = Out + (size_t)slice * O * N;
#pragma unroll
    for (int i = 0; i < 4; ++i) {
        int o = to + (ty << 2) + i;
        float g = bnp[o], bb = bnp[O + o], m = bnp[2 * O + o], vv = bnp[3 * O + o];
        float sq = sqrtf(vv + EPSF);
        float bs = bias ? bias[o] : 0.0f;
        float4 r;
        float* rp = &r.x;
#pragma unroll
        for (int j = 0; j < 4; ++j) {
            float val = acc[i][j] + bs;
            rp[j] = (val - m) / sq * g + bb;
        }
        *(float4*)&Op[(size_t)o * N + tn + (tx << 2)] = r;
    }
}

// ---------------------------------------------------------------------------
// TIM up conv3d (weights (40,10,3,3,3), pad 1 over (c,h,w)) + BN1 + inner LIF.
// Input Y layout (t,b,c,hw). Output spikes SPK layout (b,uc,c,hw).
// Grid (c=256, b=4), block 256 (hw). Each thread owns all 40 uc in regs.
// ---------------------------------------------------------------------------
__global__ __launch_bounds__(256) void tim_up(
    const float* __restrict__ Y, const float* __restrict__ w,
    const float* __restrict__ bn1, float* __restrict__ SPK)
{
    __shared__ float smem[10 * 3 * 324];   // [t][cc][18*18]
    const int c = blockIdx.x, b = blockIdx.y;
    const int tid = threadIdx.x;
    for (int idx = tid; idx < 10 * 3 * 324; idx += 256) {
        int t = idx / 972, rem = idx % 972;
        int cc = rem / 324, p = rem % 324;
        int hh = p / 18 - 1, ww = p % 18 - 1;
        int cs = c + cc - 1;
        float v = 0.0f;
        if (cs >= 0 && cs < 256 && hh >= 0 && hh < 16 && ww >= 0 && ww < 16)
            v = Y[((t * 4 + b) * 256 + cs) * 256 + hh * 16 + ww];
        smem[idx] = v;
    }
    __syncthreads();
    const int h = tid >> 4, wq = tid & 15;
    float acc[40];
#pragma unroll
    for (int i = 0; i < 40; ++i) acc[i] = 0.0f;
#pragma unroll 1
    for (int t = 0; t < 10; ++t) {
#pragma unroll
        for (int kd = 0; kd < 3; ++kd) {
            float v[9];
#pragma unroll
            for (int kh = 0; kh < 3; ++kh)
#pragma unroll
                for (int kw = 0; kw < 3; ++kw)
                    v[kh * 3 + kw] = smem[t * 972 + kd * 324 + (h + kh) * 18 + (wq + kw)];
            const float* wp = w + t * 27 + kd * 9;   // + uc*270
#pragma unroll
            for (int uc = 0; uc < 40; ++uc) {
                const float* wu = wp + uc * 270;
#pragma unroll
                for (int q = 0; q < 9; ++q)
                    acc[uc] = fmaf(wu[q], v[q], acc[uc]);
            }
        }
    }
    // BN1 (per uc)
#pragma unroll
    for (int uc = 0; uc < 40; ++uc)
        acc[uc] = (acc[uc] - bn1[80 + uc]) / sqrtf(bn1[120 + uc] + EPSF) * bn1[uc] + bn1[40 + uc];
    // Inner LIF: chain r = 0..3 over steps s (uc = 4s+r), vth = 1.0
#pragma unroll
    for (int r = 0; r < 4; ++r) {
        float mem = 0.0f;
#pragma unroll
        for (int s = 0; s < 10; ++s) {
            float xv = acc[4 * s + r];
            mem += (xv - mem) * 0.5f;
            float spk = mem > 1.0f ? 1.0f : 0.0f;
            SPK[(((size_t)b * 40 + 4 * s + r) * 256 + c) * 256 + tid] = spk;
            mem = spk > 0.0f ? 0.0f : mem;
        }
    }
}

// ---------------------------------------------------------------------------
// TIM down grouped conv3d (weights (10,4,3,3,3), groups=10) + BN2 + LIF over T.
// Input spikes (b,uc,c,hw); output spikes S layout (t,b,c,hw).
// Grid (c=256, b=4), block 256 (hw).
// ---------------------------------------------------------------------------
__global__ __launch_bounds__(256) void tim_down(
    const float* __restrict__ SPK, const float* __restrict__ w,
    const float* __restrict__ bn2, float* __restrict__ S)
{
    __shared__ float smem[4 * 3 * 324];   // [r][cc][18*18], reloaded per t
    const int c = blockIdx.x, b = blockIdx.y;
    const int tid = threadIdx.x;
    const int h = tid >> 4, wq = tid & 15;
    float mem = 0.0f;
    for (int t = 0; t < 10; ++t) {
        __syncthreads();
        for (int idx = tid; idx < 4 * 3 * 324; idx += 256) {
            int r = idx / 972, rem = idx % 972;
            int cc = rem / 324, p = rem % 324;
            int hh = p / 18 - 1, ww = p % 18 - 1;
            int cs = c + cc - 1;
            float v = 0.0f;
            if (cs >= 0 && cs < 256 && hh >= 0 && hh < 16 && ww >= 0 && ww < 16)
                v = SPK[(((size_t)b * 40 + 4 * t + r) * 256 + cs) * 256 + hh * 16 + ww];
            smem[idx] = v;
        }
        __syncthreads();
        float a = 0.0f;
#pragma unroll
        for (int r = 0; r < 4; ++r)
#pragma unroll
            for (int kd = 0; kd < 3; ++kd) {
                const float* wp = w + ((t * 4 + r) * 3 + kd) * 9;
#pragma unroll
                for (int kh = 0; kh < 3; ++kh)
#pragma unroll
                    for (int kw = 0; kw < 3; ++kw)
                        a = fmaf(wp[kh * 3 + kw],
                                 smem[r * 972 + kd * 324 + (h + kh) * 18 + (wq + kw)], a);
            }
        a = (a - bn2[20 + t]) / sqrtf(bn2[30 + t] + EPSF) * bn2[t] + bn2[10 + t];
        mem += (a - mem) * 0.5f;
        float spk = mem > 1.0f ? 1.0f : 0.0f;
        S[((t * 4 + b) * 256 + c) * 256 + tid] = spk;
        mem = spk > 0.0f ? 0.0f : mem;
    }
}

// ---------------------------------------------------------------------------
// ktv[t,b,hd,j,j2] = sum_n K[t,b,hd*16+j,n] * V[t,b,hd*16+j2,n]  (exact ints)
// Grid 640 (t*b*hd), block 256 = (j,j2).
// ---------------------------------------------------------------------------
__global__ __launch_bounds__(256) void ktv_k(
    const float* __restrict__ SK, const float* __restrict__ SV,
    float* __restrict__ KTV)
{
    __shared__ float ks[16 * 257], vs[16 * 257];
    const int bi = blockIdx.x;
    const int t = bi >> 6, b = (bi >> 4) & 3, hd = bi & 15;
    const int tid = threadIdx.x;
    for (int i = tid; i < 4096; i += 256) {
        int row = i >> 8, col = i & 255;
        ks[row * 257 + col] = SK[((t * 4 + b) * 256 + hd * 16 + row) * 256 + col];
        vs[row * 257 + col] = SV[((t * 4 + b) * 256 + hd * 16 + row) * 256 + col];
    }
    __syncthreads();
    const int j = tid >> 4, j2 = tid & 15;
    float a = 0.0f;
#pragma unroll 8
    for (int n = 0; n < 256; ++n)
        a = fmaf(ks[j * 257 + n], vs[j2 * 257 + n], a);
    KTV[((t * 4 + b) * 16 + hd) * 256 + tid] = a;
}

// ---------------------------------------------------------------------------
// o = q @ ktv * 0.25 (exact) fused with attn_lif (vth=0.5) -> spikes (t,b,c,n)
// Grid 256 = (b, hd, n-quarter), block 64 (n). Thread owns 16 j2 chains.
// ---------------------------------------------------------------------------
__global__ __launch_bounds__(64) void attn_k(
    const float* __restrict__ SQ, const float* __restrict__ KTV,
    float* __restrict__ OSPK)
{
    __shared__ float kt[2560];   // [t][j*16+j2]
    const int x = blockIdx.x;
    const int b = x >> 6, hd = (x >> 2) & 15, nq = x & 3;
    const int tid = threadIdx.x;
    const int n = nq * 64 + tid;
    for (int i = tid; i < 2560; i += 64) {
        int t = i >> 8;
        kt[i] = KTV[((t * 4 + b) * 16 + hd) * 256 + (i & 255)];
    }
    __syncthreads();
    float mem[16];
#pragma unroll
    for (int i = 0; i < 16; ++i) mem[i] = 0.0f;
    for (int t = 0; t < 10; ++t) {
        float q[16];
#pragma unroll
        for (int j = 0; j < 16; ++j)
            q[j] = SQ[((t * 4 + b) * 256 + hd * 16 + j) * 256 + n];
#pragma unroll
        for (int j2 = 0; j2 < 16; ++j2) {
            float a = 0.0f;
#pragma unroll
            for (int j = 0; j < 16; ++j)
                a = fmaf(q[j], kt[t * 256 + j * 16 + j2], a);
            a *= 0.25f;
            mem[j2] += (a - mem[j2]) * 0.5f;
            float spk = mem[j2] > 0.5f ? 1.0f : 0.0f;
            OSPK[((t * 4 + b) * 256 + hd * 16 + j2) * 256 + n] = spk;
            mem[j2] = spk > 0.0f ? 0.0f : mem[j2];
        }
    }
}

// LIF over T (vth=1) on P, then H = x + spikes.
// SSA tensors: per-t slice = B*C*H*W = 262,144 elems. Grid 1024 x 256.
__global__ __launch_bounds__(256) void ssa_lif_res(
    const float* __restrict__ P, const float* __restrict__ x,
    float* __restrict__ H)
{
    const int idx = blockIdx.x * 256 + threadIdx.x;
    float mem = 0.0f;
    for (int t = 0; t < 10; ++t) {
        float v = P[t * 262144 + idx];
        mem += (v - mem) * 0.5f;
        float spk = mem > 1.0f ? 1.0f : 0.0f;
        H[t * 262144 + idx] = x[t * 262144 + idx] + spk;
        mem = spk > 0.0f ? 0.0f : mem;
    }
}

// In-place LIF over T (vth=1) on fc1 activations (t,b,1024,hw):
// per-t slice = 4*1024*256 = 1,048,576 elems. Grid 4096 x 256.
__global__ __launch_bounds__(256) void lif_ip(float* __restrict__ A)
{
    const int idx = blockIdx.x * 256 + threadIdx.x;
    float mem = 0.0f;
    for (int t = 0; t < 10; ++t) {
        float v = A[t * 1048576 + idx];
        mem += (v - mem) * 0.5f;
        float spk = mem > 1.0f ? 1.0f : 0.0f;
        A[t * 1048576 + idx] = spk;
        mem = spk > 0.0f ? 0.0f : mem;
    }
}

// out = H + lif(P) over T (vth=1). Per-t slice 262,144. Grid 1024 x 256.
__global__ __launch_bounds__(256) void final_k(
    const float* __restrict__ P, const float* __restrict__ H,
    float* __restrict__ out)
{
    const int idx = blockIdx.x * 256 + threadIdx.x;
    float mem = 0.0f;
    for (int t = 0; t < 10; ++t) {
        float v = P[t * 262144 + idx];
        mem += (v - mem) * 0.5f;
        float spk = mem > 1.0f ? 1.0f : 0.0f;
        out[t * 262144 + idx] = H[t * 262144 + idx] + spk;
        mem = spk > 0.0f ? 0.0f : mem;
    }
}

// ---------------------------------------------------------------------------
extern "C" void kernel_launch(void* const* d_in, const int* in_sizes, int n_in,
                              void* d_out, int out_size, void* d_ws, size_t ws_size,
                              hipStream_t stream)
{
    const float* x        = (const float*)d_in[0];
    const float* q_w      = (const float*)d_in[1];
    const float* q_bn     = (const float*)d_in[2];
    const float* k_w      = (const float*)d_in[3];
    const float* k_bn     = (const float*)d_in[4];
    const float* v_w      = (const float*)d_in[5];
    const float* v_bn     = (const float*)d_in[6];
    const float* proj_w   = (const float*)d_in[7];
    const float* proj_bn  = (const float*)d_in[8];
    const float* up_w     = (const float*)d_in[9];
    const float* bn1      = (const float*)d_in[10];
    const float* down_w   = (const float*)d_in[11];
    const float* bn2      = (const float*)d_in[12];
    const float* fc1_w    = (const float*)d_in[13];
    const float* fc1_b    = (const float*)d_in[14];
    const float* fc1_bn   = (const float*)d_in[15];
    const float* fc2_w    = (const float*)d_in[16];
    const float* fc2_b    = (const float*)d_in[17];
    const float* fc2_bn   = (const float*)d_in[18];

    float* ws   = (float*)d_ws;
    float* Y    = ws;                    // 2,621,440  (branch BN out / attn spikes)
    float* ASPK = Y + 2621440;           // 10,485,760 (up spikes / fc1 out+spikes)
    float* SQ   = ASPK + 10485760;       // 2,621,440  (q spikes / proj out)
    float* SK   = SQ + 2621440;          // 2,621,440  (k spikes / fc2 out)
    float* SV   = SK + 2621440;          // 2,621,440  (v spikes / H)
    float* KTV  = SV + 2621440;          // 163,840
    // total ws: 21,135,360 floats = 84.5 MB

    const float* Wb[3]  = {q_w, k_w, v_w};
    const float* BNb[3] = {q_bn, k_bn, v_bn};
    float* Sb[3] = {SQ, SK, SV};

    for (int br = 0; br < 3; ++br) {
        gemm_bn<<<dim3(16, 40), 256, 0, stream>>>(Wb[br], x, Y, BNb[br], nullptr, 256, 256, 256);
        tim_up<<<dim3(256, 4), 256, 0, stream>>>(Y, up_w, bn1, ASPK);
        tim_down<<<dim3(256, 4), 256, 0, stream>>>(ASPK, down_w, bn2, Sb[br]);
    }
    ktv_k<<<640, 256, 0, stream>>>(SK, SV, KTV);
    attn_k<<<256, 64, 0, stream>>>(SQ, KTV, Y);                 // Y <- attn spikes
    gemm_bn<<<dim3(16, 40), 256, 0, stream>>>(proj_w, Y, SQ, proj_bn, nullptr, 256, 256, 256);
    ssa_lif_res<<<1024, 256, 0, stream>>>(SQ, x, SV);           // SV <- H
    gemm_bn<<<dim3(64, 40), 256, 0, stream>>>(fc1_w, SV, ASPK, fc1_bn, fc1_b, 1024, 256, 256);
    lif_ip<<<4096, 256, 0, stream>>>(ASPK);
    gemm_bn<<<dim3(16, 40), 256, 0, stream>>>(fc2_w, ASPK, SK, fc2_bn, fc2_b, 256, 1024, 256);
    final_k<<<1024, 256, 0, stream>>>(SK, SV, (float*)d_out);
}

// Round 3
// 1002.222 us; speedup vs baseline: 1.7950x; 1.7950x over previous
//
#include <hip/hip_runtime.h>
#include <cstdint>
#include <cstddef>

// Problem dims (fixed)
// T=10 B=4 C=256 H=W=16 N=256 HEADS=16 d=16 HID=1024 UC=40 STEP=10 R=4
#define EPSF 1e-5f

// ---------------------------------------------------------------------------
// Generic fp32 tiled GEMM with fused bias + batchnorm epilogue.
// Out[slice][o][n] = bn( sum_k W[o][k] * X[slice][k][n] + bias[o] )
// Grid: x = (O/64)*(N/64), y = slices. Block 256.
// ---------------------------------------------------------------------------
__global__ __launch_bounds__(256) void gemm_bn(
    const float* __restrict__ W, const float* __restrict__ X,
    float* __restrict__ Out, const float* __restrict__ bnp,
    const float* __restrict__ bias, int O, int K, int N)
{
    __shared__ float As[16][68];   // [k][o], padded rows (16B-aligned)
    __shared__ float Bs[16][68];   // [k][n]
    const int slice  = blockIdx.y;
    const int tilesn = N >> 6;
    const int to = (blockIdx.x / tilesn) << 6;
    const int tn = (blockIdx.x % tilesn) << 6;
    const float* Xs = X + (size_t)slice * K * N;
    const int tid = threadIdx.x;
    const int tx = tid & 15, ty = tid >> 4;
    const int ol = tid >> 2, kl = (tid & 3) << 2;     // W-tile load coords
    const int krow = tid >> 4, ncol = (tid & 15) << 2; // X-tile load coords

    float acc[4][4];
#pragma unroll
    for (int i = 0; i < 4; ++i)
#pragma unroll
        for (int j = 0; j < 4; ++j) acc[i][j] = 0.0f;

    for (int k0 = 0; k0 < K; k0 += 16) {
        float4 wv = *(const float4*)&W[(size_t)(to + ol) * K + k0 + kl];
        float4 xv = *(const float4*)&Xs[(size_t)(k0 + krow) * N + tn + ncol];
        __syncthreads();
        As[kl + 0][ol] = wv.x; As[kl + 1][ol] = wv.y;
        As[kl + 2][ol] = wv.z; As[kl + 3][ol] = wv.w;
        *(float4*)&Bs[krow][ncol] = xv;
        __syncthreads();
#pragma unroll
        for (int kk = 0; kk < 16; ++kk) {
            float4 av = *(const float4*)&As[kk][ty << 2];
            float4 bv = *(const float4*)&Bs[kk][tx << 2];
            float a[4] = {av.x, av.y, av.z, av.w};
            float b[4] = {bv.x, bv.y, bv.z, bv.w};
#pragma unroll
            for (int i = 0; i < 4; ++i)
#pragma unroll
                for (int j = 0; j < 4; ++j)
                    acc[i][j] = fmaf(a[i], b[j], acc[i][j]);
        }
    }
    float* Op = Out + (size_t)slice * O * N;
#pragma unroll
    for (int i = 0; i < 4; ++i) {
        int o = to + (ty << 2) + i;
        float g = bnp[o], bb = bnp[O + o], m = bnp[2 * O + o], vv = bnp[3 * O + o];
        float sq = sqrtf(vv + EPSF);
        float bs = bias ? bias[o] : 0.0f;
        float4 r;
        float* rp = &r.x;
#pragma unroll
        for (int j = 0; j < 4; ++j) {
            float val = acc[i][j] + bs;
            rp[j] = (val - m) / sq * g + bb;
        }
        *(float4*)&Op[(size_t)o * N + tn + (tx << 2)] = r;
    }
}

// ---------------------------------------------------------------------------
// Weight pre-transpose for tim_up: WT[(t*27+kd*9+q)*48 + g*12 + u] =
//   up_w[(4u+g)*270 + t*27 + kd*9 + q]  (u<10; pad slots 10,11 = 0)
// 12,960 elements.
// ---------------------------------------------------------------------------
__global__ __launch_bounds__(256) void wt_k(
    const float* __restrict__ up_w, float* __restrict__ WT)
{
    int idx = blockIdx.x * 256 + threadIdx.x;
    if (idx >= 12960) return;
    int slot = idx % 48, tq = idx / 48;      // tq = t*27 + kd*9 + q
    int g = slot / 12, u = slot % 12;
    float v = 0.0f;
    if (u < 10) v = up_w[(4 * u + g) * 270 + tq];
    WT[idx] = v;
}

// ---------------------------------------------------------------------------
// TIM up conv3d + BN1 + inner LIF, v2.
// Input Y layout (t,b,c,hw). Output spikes SPK layout (b,uc,c,hw).
// Grid (c=256, b=4), block 256 = 4 waves.
// Wave g owns uc residue class {4s+g} (one inner-LIF chain per pixel).
// Each thread owns 4 pixels (h column) x 10 steps => acc[4][10].
// Weights read wave-uniformly from WT (scalar loads).
// ---------------------------------------------------------------------------
__global__ __launch_bounds__(256) void tim_up2(
    const float* __restrict__ Y, const float* __restrict__ WT,
    const float* __restrict__ bn1, float* __restrict__ SPK)
{
    __shared__ float smem[10 * 972];   // [t][cc(3)][18*18]
    const int c = blockIdx.x, b = blockIdx.y;
    const int tid = threadIdx.x;
    for (int idx = tid; idx < 9720; idx += 256) {
        int t = idx / 972, rem = idx % 972;
        int cc = rem / 324, p = rem % 324;
        int hh = p / 18 - 1, ww = p % 18 - 1;
        int cs = c + cc - 1;
        float v = 0.0f;
        if (cs >= 0 && cs < 256 && hh >= 0 && hh < 16 && ww >= 0 && ww < 16)
            v = Y[((t * 4 + b) * 256 + cs) * 256 + hh * 16 + ww];
        smem[idx] = v;
    }
    __syncthreads();

    const int lane = tid & 63;
    const int g = __builtin_amdgcn_readfirstlane(tid >> 6);  // wave-uniform residue
    const int hb = (lane >> 4) << 2;   // 0,4,8,12
    const int wc = lane & 15;

    float acc[4][10];
#pragma unroll
    for (int i = 0; i < 4; ++i)
#pragma unroll
        for (int u = 0; u < 10; ++u) acc[i][u] = 0.0f;

#pragma unroll 1
    for (int t = 0; t < 10; ++t) {
#pragma unroll
        for (int kd = 0; kd < 3; ++kd) {
            const float* sp = &smem[t * 972 + kd * 324 + hb * 18 + wc];
            float vr[6][3];
#pragma unroll
            for (int r = 0; r < 6; ++r)
#pragma unroll
                for (int kc = 0; kc < 3; ++kc)
                    vr[r][kc] = sp[r * 18 + kc];
#pragma unroll
            for (int q = 0; q < 9; ++q) {
                const int kh = q / 3, kw = q % 3;
                const float4* wp = (const float4*)&WT[(t * 27 + kd * 9 + q) * 48 + g * 12];
                float4 w0 = wp[0], w1 = wp[1];
                float4 w2 = wp[2];
                float wr[10] = {w0.x, w0.y, w0.z, w0.w, w1.x, w1.y, w1.z, w1.w, w2.x, w2.y};
#pragma unroll
                for (int u = 0; u < 10; ++u)
#pragma unroll
                    for (int i = 0; i < 4; ++i)
                        acc[i][u] = fmaf(wr[u], vr[i + kh][kw], acc[i][u]);
            }
        }
    }

    // BN1 + inner LIF (chain over s for this wave's residue g), vth = 1.0
#pragma unroll
    for (int i = 0; i < 4; ++i) {
        float mem = 0.0f;
#pragma unroll
        for (int s = 0; s < 10; ++s) {
            const int uc = 4 * s + g;
            float ga = bn1[uc], be = bn1[40 + uc], mu = bn1[80 + uc], va = bn1[120 + uc];
            float xv = (acc[i][s] - mu) / sqrtf(va + EPSF) * ga + be;
            mem += (xv - mem) * 0.5f;
            float spk = mem > 1.0f ? 1.0f : 0.0f;
            SPK[(((size_t)b * 40 + uc) * 256 + c) * 256 + (hb + i) * 16 + wc] = spk;
            mem = spk > 0.0f ? 0.0f : mem;
        }
    }
}

// ---------------------------------------------------------------------------
// TIM down grouped conv3d (weights (10,4,3,3,3), groups=10) + BN2 + LIF over T.
// Input spikes (b,uc,c,hw); output spikes S layout (t,b,c,hw).
// Grid (c=256, b=4), block 256 (hw).
// ---------------------------------------------------------------------------
__global__ __launch_bounds__(256) void tim_down(
    const float* __restrict__ SPK, const float* __restrict__ w,
    const float* __restrict__ bn2, float* __restrict__ S)
{
    __shared__ float smem[4 * 3 * 324];   // [r][cc][18*18], reloaded per t
    const int c = blockIdx.x, b = blockIdx.y;
    const int tid = threadIdx.x;
    const int h = tid >> 4, wq = tid & 15;
    float mem = 0.0f;
    for (int t = 0; t < 10; ++t) {
        __syncthreads();
        for (int idx = tid; idx < 4 * 3 * 324; idx += 256) {
            int r = idx / 972, rem = idx % 972;
            int cc = rem / 324, p = rem % 324;
            int hh = p / 18 - 1, ww = p % 18 - 1;
            int cs = c + cc - 1;
            float v = 0.0f;
            if (cs >= 0 && cs < 256 && hh >= 0 && hh < 16 && ww >= 0 && ww < 16)
                v = SPK[(((size_t)b * 40 + 4 * t + r) * 256 + cs) * 256 + hh * 16 + ww];
            smem[idx] = v;
        }
        __syncthreads();
        float a = 0.0f;
#pragma unroll
        for (int r = 0; r < 4; ++r)
#pragma unroll
            for (int kd = 0; kd < 3; ++kd) {
                const float* wp = w + ((t * 4 + r) * 3 + kd) * 9;
#pragma unroll
                for (int kh = 0; kh < 3; ++kh)
#pragma unroll
                    for (int kw = 0; kw < 3; ++kw)
                        a = fmaf(wp[kh * 3 + kw],
                                 smem[r * 972 + kd * 324 + (h + kh) * 18 + (wq + kw)], a);
            }
        a = (a - bn2[20 + t]) / sqrtf(bn2[30 + t] + EPSF) * bn2[t] + bn2[10 + t];
        mem += (a - mem) * 0.5f;
        float spk = mem > 1.0f ? 1.0f : 0.0f;
        S[((t * 4 + b) * 256 + c) * 256 + tid] = spk;
        mem = spk > 0.0f ? 0.0f : mem;
    }
}

// ---------------------------------------------------------------------------
// ktv[t,b,hd,j,j2] = sum_n K[t,b,hd*16+j,n] * V[t,b,hd*16+j2,n]  (exact ints)
// Grid 640 (t*b*hd), block 256 = (j,j2).
// ---------------------------------------------------------------------------
__global__ __launch_bounds__(256) void ktv_k(
    const float* __restrict__ SK, const float* __restrict__ SV,
    float* __restrict__ KTV)
{
    __shared__ float ks[16 * 257], vs[16 * 257];
    const int bi = blockIdx.x;
    const int t = bi >> 6, b = (bi >> 4) & 3, hd = bi & 15;
    const int tid = threadIdx.x;
    for (int i = tid; i < 4096; i += 256) {
        int row = i >> 8, col = i & 255;
        ks[row * 257 + col] = SK[((t * 4 + b) * 256 + hd * 16 + row) * 256 + col];
        vs[row * 257 + col] = SV[((t * 4 + b) * 256 + hd * 16 + row) * 256 + col];
    }
    __syncthreads();
    const int j = tid >> 4, j2 = tid & 15;
    float a = 0.0f;
#pragma unroll 8
    for (int n = 0; n < 256; ++n)
        a = fmaf(ks[j * 257 + n], vs[j2 * 257 + n], a);
    KTV[((t * 4 + b) * 16 + hd) * 256 + tid] = a;
}

// ---------------------------------------------------------------------------
// o = q @ ktv * 0.25 (exact) fused with attn_lif (vth=0.5) -> spikes (t,b,c,n)
// Grid 256 = (b, hd, n-quarter), block 64 (n). Thread owns 16 j2 chains.
// ---------------------------------------------------------------------------
__global__ __launch_bounds__(64) void attn_k(
    const float* __restrict__ SQ, const float* __restrict__ KTV,
    float* __restrict__ OSPK)
{
    __shared__ float kt[2560];   // [t][j*16+j2]
    const int x = blockIdx.x;
    const int b = x >> 6, hd = (x >> 2) & 15, nq = x & 3;
    const int tid = threadIdx.x;
    const int n = nq * 64 + tid;
    for (int i = tid; i < 2560; i += 64) {
        int t = i >> 8;
        kt[i] = KTV[((t * 4 + b) * 16 + hd) * 256 + (i & 255)];
    }
    __syncthreads();
    float mem[16];
#pragma unroll
    for (int i = 0; i < 16; ++i) mem[i] = 0.0f;
    for (int t = 0; t < 10; ++t) {
        float q[16];
#pragma unroll
        for (int j = 0; j < 16; ++j)
            q[j] = SQ[((t * 4 + b) * 256 + hd * 16 + j) * 256 + n];
#pragma unroll
        for (int j2 = 0; j2 < 16; ++j2) {
            float a = 0.0f;
#pragma unroll
            for (int j = 0; j < 16; ++j)
                a = fmaf(q[j], kt[t * 256 + j * 16 + j2], a);
            a *= 0.25f;
            mem[j2] += (a - mem[j2]) * 0.5f;
            float spk = mem[j2] > 0.5f ? 1.0f : 0.0f;
            OSPK[((t * 4 + b) * 256 + hd * 16 + j2) * 256 + n] = spk;
            mem[j2] = spk > 0.0f ? 0.0f : mem[j2];
        }
    }
}

// LIF over T (vth=1) on P, then H = x + spikes.
// SSA tensors: per-t slice = B*C*H*W = 262,144 elems. Grid 1024 x 256.
__global__ __launch_bounds__(256) void ssa_lif_res(
    const float* __restrict__ P, const float* __restrict__ x,
    float* __restrict__ H)
{
    const int idx = blockIdx.x * 256 + threadIdx.x;
    float mem = 0.0f;
    for (int t = 0; t < 10; ++t) {
        float v = P[t * 262144 + idx];
        mem += (v - mem) * 0.5f;
        float spk = mem > 1.0f ? 1.0f : 0.0f;
        H[t * 262144 + idx] = x[t * 262144 + idx] + spk;
        mem = spk > 0.0f ? 0.0f : mem;
    }
}

// In-place LIF over T (vth=1) on fc1 activations (t,b,1024,hw):
// per-t slice = 4*1024*256 = 1,048,576 elems. Grid 4096 x 256.
__global__ __launch_bounds__(256) void lif_ip(float* __restrict__ A)
{
    const int idx = blockIdx.x * 256 + threadIdx.x;
    float mem = 0.0f;
    for (int t = 0; t < 10; ++t) {
        float v = A[t * 1048576 + idx];
        mem += (v - mem) * 0.5f;
        float spk = mem > 1.0f ? 1.0f : 0.0f;
        A[t * 1048576 + idx] = spk;
        mem = spk > 0.0f ? 0.0f : mem;
    }
}

// out = H + lif(P) over T (vth=1). Per-t slice 262,144. Grid 1024 x 256.
__global__ __launch_bounds__(256) void final_k(
    const float* __restrict__ P, const float* __restrict__ H,
    float* __restrict__ out)
{
    const int idx = blockIdx.x * 256 + threadIdx.x;
    float mem = 0.0f;
    for (int t = 0; t < 10; ++t) {
        float v = P[t * 262144 + idx];
        mem += (v - mem) * 0.5f;
        float spk = mem > 1.0f ? 1.0f : 0.0f;
        out[t * 262144 + idx] = H[t * 262144 + idx] + spk;
        mem = spk > 0.0f ? 0.0f : mem;
    }
}

// ---------------------------------------------------------------------------
extern "C" void kernel_launch(void* const* d_in, const int* in_sizes, int n_in,
                              void* d_out, int out_size, void* d_ws, size_t ws_size,
                              hipStream_t stream)
{
    const float* x        = (const float*)d_in[0];
    const float* q_w      = (const float*)d_in[1];
    const float* q_bn     = (const float*)d_in[2];
    const float* k_w      = (const float*)d_in[3];
    const float* k_bn     = (const float*)d_in[4];
    const float* v_w      = (const float*)d_in[5];
    const float* v_bn     = (const float*)d_in[6];
    const float* proj_w   = (const float*)d_in[7];
    const float* proj_bn  = (const float*)d_in[8];
    const float* up_w     = (const float*)d_in[9];
    const float* bn1      = (const float*)d_in[10];
    const float* down_w   = (const float*)d_in[11];
    const float* bn2      = (const float*)d_in[12];
    const float* fc1_w    = (const float*)d_in[13];
    const float* fc1_b    = (const float*)d_in[14];
    const float* fc1_bn   = (const float*)d_in[15];
    const float* fc2_w    = (const float*)d_in[16];
    const float* fc2_b    = (const float*)d_in[17];
    const float* fc2_bn   = (const float*)d_in[18];

    float* ws   = (float*)d_ws;
    float* Y    = ws;                    // 2,621,440  (branch BN out / attn spikes)
    float* ASPK = Y + 2621440;           // 10,485,760 (up spikes / fc1 out+spikes)
    float* SQ   = ASPK + 10485760;       // 2,621,440  (q spikes / proj out)
    float* SK   = SQ + 2621440;          // 2,621,440  (k spikes / fc2 out)
    float* SV   = SK + 2621440;          // 2,621,440  (v spikes / H)
    float* KTV  = SV + 2621440;          // 163,840  (WT during tim_up phase, then ktv)
    float* WT   = KTV;                   // 12,960 <= 163,840; dead before ktv_k runs
    // total ws: 21,135,360 floats = 84.5 MB

    const float* Wb[3]  = {q_w, k_w, v_w};
    const float* BNb[3] = {q_bn, k_bn, v_bn};
    float* Sb[3] = {SQ, SK, SV};

    wt_k<<<51, 256, 0, stream>>>(up_w, WT);
    for (int br = 0; br < 3; ++br) {
        gemm_bn<<<dim3(16, 40), 256, 0, stream>>>(Wb[br], x, Y, BNb[br], nullptr, 256, 256, 256);
        tim_up2<<<dim3(256, 4), 256, 0, stream>>>(Y, WT, bn1, ASPK);
        tim_down<<<dim3(256, 4), 256, 0, stream>>>(ASPK, down_w, bn2, Sb[br]);
    }
    ktv_k<<<640, 256, 0, stream>>>(SK, SV, KTV);
    attn_k<<<256, 64, 0, stream>>>(SQ, KTV, Y);                 // Y <- attn spikes
    gemm_bn<<<dim3(16, 40), 256, 0, stream>>>(proj_w, Y, SQ, proj_bn, nullptr, 256, 256, 256);
    ssa_lif_res<<<1024, 256, 0, stream>>>(SQ, x, SV);           // SV <- H
    gemm_bn<<<dim3(64, 40), 256, 0, stream>>>(fc1_w, SV, ASPK, fc1_bn, fc1_b, 1024, 256, 256);
    lif_ip<<<4096, 256, 0, stream>>>(ASPK);
    gemm_bn<<<dim3(16, 40), 256, 0, stream>>>(fc2_w, ASPK, SK, fc2_bn, fc2_b, 256, 1024, 256);
    final_k<<<1024, 256, 0, stream>>>(SK, SV, (float*)d_out);
}

// Round 4
// 825.691 us; speedup vs baseline: 2.1787x; 1.2138x over previous
//
#include <hip/hip_runtime.h>
#include <cstdint>
#include <cstddef>

// Problem dims (fixed)
// T=10 B=4 C=256 H=W=16 N=256 HEADS=16 d=16 HID=1024 UC=40 STEP=10 R=4
#define EPSF 1e-5f

// ---------------------------------------------------------------------------
// Generic fp32 tiled GEMM with fused bias + batchnorm epilogue.
// Out[slice][o][n] = bn( sum_k W[o][k] * X[slice][k][n] + bias[o] )
// Grid: x = (O/64)*(N/64), y = slices. Block 256.
// ---------------------------------------------------------------------------
__global__ __launch_bounds__(256) void gemm_bn(
    const float* __restrict__ W, const float* __restrict__ X,
    float* __restrict__ Out, const float* __restrict__ bnp,
    const float* __restrict__ bias, int O, int K, int N)
{
    __shared__ float As[16][68];   // [k][o], padded rows (16B-aligned)
    __shared__ float Bs[16][68];   // [k][n]
    const int slice  = blockIdx.y;
    const int tilesn = N >> 6;
    const int to = (blockIdx.x / tilesn) << 6;
    const int tn = (blockIdx.x % tilesn) << 6;
    const float* Xs = X + (size_t)slice * K * N;
    const int tid = threadIdx.x;
    const int tx = tid & 15, ty = tid >> 4;
    const int ol = tid >> 2, kl = (tid & 3) << 2;     // W-tile load coords
    const int krow = tid >> 4, ncol = (tid & 15) << 2; // X-tile load coords

    float acc[4][4];
#pragma unroll
    for (int i = 0; i < 4; ++i)
#pragma unroll
        for (int j = 0; j < 4; ++j) acc[i][j] = 0.0f;

    for (int k0 = 0; k0 < K; k0 += 16) {
        float4 wv = *(const float4*)&W[(size_t)(to + ol) * K + k0 + kl];
        float4 xv = *(const float4*)&Xs[(size_t)(k0 + krow) * N + tn + ncol];
        __syncthreads();
        As[kl + 0][ol] = wv.x; As[kl + 1][ol] = wv.y;
        As[kl + 2][ol] = wv.z; As[kl + 3][ol] = wv.w;
        *(float4*)&Bs[krow][ncol] = xv;
        __syncthreads();
#pragma unroll
        for (int kk = 0; kk < 16; ++kk) {
            float4 av = *(const float4*)&As[kk][ty << 2];
            float4 bv = *(const float4*)&Bs[kk][tx << 2];
            float a[4] = {av.x, av.y, av.z, av.w};
            float b[4] = {bv.x, bv.y, bv.z, bv.w};
#pragma unroll
            for (int i = 0; i < 4; ++i)
#pragma unroll
                for (int j = 0; j < 4; ++j)
                    acc[i][j] = fmaf(a[i], b[j], acc[i][j]);
        }
    }
    float* Op = Out + (size_t)slice * O * N;
#pragma unroll
    for (int i = 0; i < 4; ++i) {
        int o = to + (ty << 2) + i;
        float g = bnp[o], bb = bnp[O + o], m = bnp[2 * O + o], vv = bnp[3 * O + o];
        float sq = sqrtf(vv + EPSF);
        float bs = bias ? bias[o] : 0.0f;
        float4 r;
        float* rp = &r.x;
#pragma unroll
        for (int j = 0; j < 4; ++j) {
            float val = acc[i][j] + bs;
            rp[j] = (val - m) / sq * g + bb;
        }
        *(float4*)&Op[(size_t)o * N + tn + (tx << 2)] = r;
    }
}

// ---------------------------------------------------------------------------
// Weight pre-transpose for tim_up: WT[(t*27+kd*9+q)*48 + g*12 + u] =
//   up_w[(4u+g)*270 + t*27 + kd*9 + q]  (u<10; pad slots 10,11 = 0)
// ---------------------------------------------------------------------------
__global__ __launch_bounds__(256) void wt_k(
    const float* __restrict__ up_w, float* __restrict__ WT)
{
    int idx = blockIdx.x * 256 + threadIdx.x;
    if (idx >= 12960) return;
    int slot = idx % 48, tq = idx / 48;      // tq = t*27 + kd*9 + q
    int g = slot / 12, u = slot % 12;
    float v = 0.0f;
    if (u < 10) v = up_w[(4 * u + g) * 270 + tq];
    WT[idx] = v;
}

// ---------------------------------------------------------------------------
// TIM up conv3d + BN1 + inner LIF, v3: half-plane blocks.
// Input Y layout (t,b,c,hw). Output spikes SPK layout (b,uc,c,hw).
// Grid (c=256, b*2=8), block 256 = 4 waves. Wave g owns uc residue {4s+g}.
// Each thread owns 2 pixels (h pair). LDS row stride 20 (bank-friendly).
// ---------------------------------------------------------------------------
__global__ __launch_bounds__(256) void tim_up3(
    const float* __restrict__ Y, const float* __restrict__ WT,
    const float* __restrict__ bn1, float* __restrict__ SPK)
{
    __shared__ float smem[10 * 3 * 200];   // [t][cc][10 rows x 20 cols]
    const int c = blockIdx.x;
    const int b = blockIdx.y >> 1, half = blockIdx.y & 1;
    const int tid = threadIdx.x;
    for (int idx = tid; idx < 6000; idx += 256) {
        int t = idx / 600, rem = idx % 600;
        int cc = rem / 200, p = rem % 200;
        int rr = p / 20, col = p % 20;
        int h = half * 8 + rr - 1, ww = col - 1;
        int cs = c + cc - 1;
        float v = 0.0f;
        if (cs >= 0 && cs < 256 && h >= 0 && h < 16 && ww >= 0 && ww < 16)
            v = Y[((t * 4 + b) * 256 + cs) * 256 + h * 16 + ww];
        smem[idx] = v;
    }
    __syncthreads();

    const int lane = tid & 63;
    const int g = __builtin_amdgcn_readfirstlane(tid >> 6);  // wave-uniform residue
    const int hb2 = (lane >> 4) << 1;   // 0,2,4,6 (local row-pair base)
    const int wc = lane & 15;

    float acc[2][10];
#pragma unroll
    for (int i = 0; i < 2; ++i)
#pragma unroll
        for (int u = 0; u < 10; ++u) acc[i][u] = 0.0f;

#pragma unroll 1
    for (int t = 0; t < 10; ++t) {
#pragma unroll
        for (int kd = 0; kd < 3; ++kd) {
            const float* sp = &smem[t * 600 + kd * 200 + hb2 * 20 + wc];
            float vr[4][3];
#pragma unroll
            for (int r = 0; r < 4; ++r)
#pragma unroll
                for (int kc = 0; kc < 3; ++kc)
                    vr[r][kc] = sp[r * 20 + kc];
#pragma unroll
            for (int q = 0; q < 9; ++q) {
                const int kh = q / 3, kw = q % 3;
                const float4* wp = (const float4*)&WT[(t * 27 + kd * 9 + q) * 48 + g * 12];
                float4 w0 = wp[0], w1 = wp[1];
                float4 w2 = wp[2];
                float wr[10] = {w0.x, w0.y, w0.z, w0.w, w1.x, w1.y, w1.z, w1.w, w2.x, w2.y};
#pragma unroll
                for (int u = 0; u < 10; ++u)
#pragma unroll
                    for (int i = 0; i < 2; ++i)
                        acc[i][u] = fmaf(wr[u], vr[i + kh][kw], acc[i][u]);
            }
        }
    }

    // BN1 + inner LIF (chain over s for this wave's residue g), vth = 1.0
#pragma unroll
    for (int i = 0; i < 2; ++i) {
        const int h = half * 8 + hb2 + i;
        float mem = 0.0f;
#pragma unroll
        for (int s = 0; s < 10; ++s) {
            const int uc = 4 * s + g;
            float ga = bn1[uc], be = bn1[40 + uc], mu = bn1[80 + uc], va = bn1[120 + uc];
            float xv = (acc[i][s] - mu) / sqrtf(va + EPSF) * ga + be;
            mem += (xv - mem) * 0.5f;
            float spk = mem > 1.0f ? 1.0f : 0.0f;
            SPK[(((size_t)b * 40 + uc) * 256 + c) * 256 + h * 16 + wc] = spk;
            mem = spk > 0.0f ? 0.0f : mem;
        }
    }
}

// ---------------------------------------------------------------------------
// TIM down grouped conv3d, t-parallel: grid (c=256, b=4, t=10), block 256.
// Computes BN2'd pre-LIF value -> PreY layout (t,b,c,hw). LIF done by lif_down.
// ---------------------------------------------------------------------------
__global__ __launch_bounds__(256) void tim_down_pre(
    const float* __restrict__ SPK, const float* __restrict__ w,
    const float* __restrict__ bn2, float* __restrict__ PreY)
{
    __shared__ float smem[4 * 3 * 324];   // [r][cc][18*18]
    const int c = blockIdx.x, b = blockIdx.y, t = blockIdx.z;
    const int tid = threadIdx.x;
    for (int idx = tid; idx < 3888; idx += 256) {
        int r = idx / 972, rem = idx % 972;
        int cc = rem / 324, p = rem % 324;
        int hh = p / 18 - 1, ww = p % 18 - 1;
        int cs = c + cc - 1;
        float v = 0.0f;
        if (cs >= 0 && cs < 256 && hh >= 0 && hh < 16 && ww >= 0 && ww < 16)
            v = SPK[(((size_t)b * 40 + 4 * t + r) * 256 + cs) * 256 + hh * 16 + ww];
        smem[idx] = v;
    }
    __syncthreads();
    const int h = tid >> 4, wq = tid & 15;
    float a = 0.0f;
#pragma unroll
    for (int r = 0; r < 4; ++r)
#pragma unroll
        for (int kd = 0; kd < 3; ++kd) {
            const float* wp = w + ((t * 4 + r) * 3 + kd) * 9;
#pragma unroll
            for (int kh = 0; kh < 3; ++kh)
#pragma unroll
                for (int kw = 0; kw < 3; ++kw)
                    a = fmaf(wp[kh * 3 + kw],
                             smem[r * 972 + kd * 324 + (h + kh) * 18 + (wq + kw)], a);
        }
    a = (a - bn2[20 + t]) / sqrtf(bn2[30 + t] + EPSF) * bn2[t] + bn2[10 + t];
    PreY[((t * 4 + b) * 256 + c) * 256 + tid] = a;
}

// LIF over T (vth=1) on PreY (stride 262144), writes binary spikes to S.
__global__ __launch_bounds__(256) void lif_down(
    const float* __restrict__ PreY, float* __restrict__ S)
{
    const int idx = blockIdx.x * 256 + threadIdx.x;
    float mem = 0.0f;
    for (int t = 0; t < 10; ++t) {
        float v = PreY[t * 262144 + idx];
        mem += (v - mem) * 0.5f;
        float spk = mem > 1.0f ? 1.0f : 0.0f;
        S[t * 262144 + idx] = spk;
        mem = spk > 0.0f ? 0.0f : mem;
    }
}

// ---------------------------------------------------------------------------
// ktv[t,b,hd,j,j2] = sum_n K[..j,n] * V[..j2,n]  (exact integer dots)
// Grid 640 (t*b*hd), block 256 = (j,j2). 4-way partial sums (exact).
// ---------------------------------------------------------------------------
__global__ __launch_bounds__(256) void ktv_k(
    const float* __restrict__ SK, const float* __restrict__ SV,
    float* __restrict__ KTV)
{
    __shared__ float ks[16 * 257], vs[16 * 257];
    const int bi = blockIdx.x;
    const int t = bi >> 6, b = (bi >> 4) & 3, hd = bi & 15;
    const int tid = threadIdx.x;
    for (int i = tid; i < 4096; i += 256) {
        int row = i >> 8, col = i & 255;
        ks[row * 257 + col] = SK[((t * 4 + b) * 256 + hd * 16 + row) * 256 + col];
        vs[row * 257 + col] = SV[((t * 4 + b) * 256 + hd * 16 + row) * 256 + col];
    }
    __syncthreads();
    const int j = tid >> 4, j2 = tid & 15;
    float a0 = 0.0f, a1 = 0.0f, a2 = 0.0f, a3 = 0.0f;
#pragma unroll 4
    for (int n = 0; n < 256; n += 4) {
        a0 = fmaf(ks[j * 257 + n + 0], vs[j2 * 257 + n + 0], a0);
        a1 = fmaf(ks[j * 257 + n + 1], vs[j2 * 257 + n + 1], a1);
        a2 = fmaf(ks[j * 257 + n + 2], vs[j2 * 257 + n + 2], a2);
        a3 = fmaf(ks[j * 257 + n + 3], vs[j2 * 257 + n + 3], a3);
    }
    KTV[((t * 4 + b) * 16 + hd) * 256 + tid] = (a0 + a1) + (a2 + a3);
}

// ---------------------------------------------------------------------------
// o = q @ ktv * 0.25 (exact) fused with attn_lif (vth=0.5) -> spikes (t,b,c,n)
// Grid 1024 = (b, hd, n-group of 16), block 256 = (j2, nl). One chain/thread.
// ---------------------------------------------------------------------------
__global__ __launch_bounds__(256) void attn_k(
    const float* __restrict__ SQ, const float* __restrict__ KTV,
    float* __restrict__ OSPK)
{
    __shared__ float kt[2560];    // [t][j*16+j2]
    __shared__ float qs[16 * 17]; // [nl][j], padded
    const int x = blockIdx.x;
    const int b = x >> 8, hd = (x >> 4) & 15, ng = x & 15;
    const int tid = threadIdx.x;
    const int j2 = tid >> 4, nl = tid & 15;
    const int n = ng * 16 + nl;
    for (int i = tid; i < 2560; i += 256) {
        int t = i >> 8;
        kt[i] = KTV[((t * 4 + b) * 16 + hd) * 256 + (i & 255)];
    }
    float mem = 0.0f;
    for (int t = 0; t < 10; ++t) {
        __syncthreads();
        // thread (j2, nl) loads q[j=j2] for its n
        qs[nl * 17 + j2] = SQ[((t * 4 + b) * 256 + hd * 16 + j2) * 256 + n];
        __syncthreads();
        float a = 0.0f;
#pragma unroll
        for (int j = 0; j < 16; ++j)
            a = fmaf(qs[nl * 17 + j], kt[t * 256 + j * 16 + j2], a);
        a *= 0.25f;
        mem += (a - mem) * 0.5f;
        float spk = mem > 0.5f ? 1.0f : 0.0f;
        OSPK[((t * 4 + b) * 256 + hd * 16 + j2) * 256 + n] = spk;
        mem = spk > 0.0f ? 0.0f : mem;
    }
}

// LIF over T (vth=1) on P, then H = x + spikes. Per-t slice 262,144.
__global__ __launch_bounds__(256) void ssa_lif_res(
    const float* __restrict__ P, const float* __restrict__ x,
    float* __restrict__ H)
{
    const int idx = blockIdx.x * 256 + threadIdx.x;
    float mem = 0.0f;
    for (int t = 0; t < 10; ++t) {
        float v = P[t * 262144 + idx];
        mem += (v - mem) * 0.5f;
        float spk = mem > 1.0f ? 1.0f : 0.0f;
        H[t * 262144 + idx] = x[t * 262144 + idx] + spk;
        mem = spk > 0.0f ? 0.0f : mem;
    }
}

// In-place LIF over T (vth=1), per-t slice 1,048,576 (fc1 activations).
__global__ __launch_bounds__(256) void lif_ip(float* __restrict__ A)
{
    const int idx = blockIdx.x * 256 + threadIdx.x;
    float mem = 0.0f;
    for (int t = 0; t < 10; ++t) {
        float v = A[t * 1048576 + idx];
        mem += (v - mem) * 0.5f;
        float spk = mem > 1.0f ? 1.0f : 0.0f;
        A[t * 1048576 + idx] = spk;
        mem = spk > 0.0f ? 0.0f : mem;
    }
}

// out = H + lif(P) over T (vth=1). Per-t slice 262,144.
__global__ __launch_bounds__(256) void final_k(
    const float* __restrict__ P, const float* __restrict__ H,
    float* __restrict__ out)
{
    const int idx = blockIdx.x * 256 + threadIdx.x;
    float mem = 0.0f;
    for (int t = 0; t < 10; ++t) {
        float v = P[t * 262144 + idx];
        mem += (v - mem) * 0.5f;
        float spk = mem > 1.0f ? 1.0f : 0.0f;
        out[t * 262144 + idx] = H[t * 262144 + idx] + spk;
        mem = spk > 0.0f ? 0.0f : mem;
    }
}

// ---------------------------------------------------------------------------
extern "C" void kernel_launch(void* const* d_in, const int* in_sizes, int n_in,
                              void* d_out, int out_size, void* d_ws, size_t ws_size,
                              hipStream_t stream)
{
    const float* x        = (const float*)d_in[0];
    const float* q_w      = (const float*)d_in[1];
    const float* q_bn     = (const float*)d_in[2];
    const float* k_w      = (const float*)d_in[3];
    const float* k_bn     = (const float*)d_in[4];
    const float* v_w      = (const float*)d_in[5];
    const float* v_bn     = (const float*)d_in[6];
    const float* proj_w   = (const float*)d_in[7];
    const float* proj_bn  = (const float*)d_in[8];
    const float* up_w     = (const float*)d_in[9];
    const float* bn1      = (const float*)d_in[10];
    const float* down_w   = (const float*)d_in[11];
    const float* bn2      = (const float*)d_in[12];
    const float* fc1_w    = (const float*)d_in[13];
    const float* fc1_b    = (const float*)d_in[14];
    const float* fc1_bn   = (const float*)d_in[15];
    const float* fc2_w    = (const float*)d_in[16];
    const float* fc2_b    = (const float*)d_in[17];
    const float* fc2_bn   = (const float*)d_in[18];

    float* ws   = (float*)d_ws;
    float* Y    = ws;                    // 2,621,440  (branch BN out / down pre-LIF / attn spikes)
    float* ASPK = Y + 2621440;           // 10,485,760 (up spikes / fc1 out+spikes)
    float* SQ   = ASPK + 10485760;       // 2,621,440  (q spikes / proj out)
    float* SK   = SQ + 2621440;          // 2,621,440  (k spikes / fc2 out)
    float* SV   = SK + 2621440;          // 2,621,440  (v spikes / H)
    float* KTV  = SV + 2621440;          // 163,840  (WT during tim_up phase, then ktv)
    float* WT   = KTV;                   // 12,960 <= 163,840; dead before ktv_k runs
    // total ws: 21,135,360 floats = 84.5 MB

    const float* Wb[3]  = {q_w, k_w, v_w};
    const float* BNb[3] = {q_bn, k_bn, v_bn};
    float* Sb[3] = {SQ, SK, SV};

    wt_k<<<51, 256, 0, stream>>>(up_w, WT);
    for (int br = 0; br < 3; ++br) {
        gemm_bn<<<dim3(16, 40), 256, 0, stream>>>(Wb[br], x, Y, BNb[br], nullptr, 256, 256, 256);
        tim_up3<<<dim3(256, 8), 256, 0, stream>>>(Y, WT, bn1, ASPK);
        tim_down_pre<<<dim3(256, 4, 10), 256, 0, stream>>>(ASPK, down_w, bn2, Y);
        lif_down<<<1024, 256, 0, stream>>>(Y, Sb[br]);
    }
    ktv_k<<<640, 256, 0, stream>>>(SK, SV, KTV);
    attn_k<<<1024, 256, 0, stream>>>(SQ, KTV, Y);               // Y <- attn spikes
    gemm_bn<<<dim3(16, 40), 256, 0, stream>>>(proj_w, Y, SQ, proj_bn, nullptr, 256, 256, 256);
    ssa_lif_res<<<1024, 256, 0, stream>>>(SQ, x, SV);           // SV <- H
    gemm_bn<<<dim3(64, 40), 256, 0, stream>>>(fc1_w, SV, ASPK, fc1_bn, fc1_b, 1024, 256, 256);
    lif_ip<<<4096, 256, 0, stream>>>(ASPK);
    gemm_bn<<<dim3(16, 40), 256, 0, stream>>>(fc2_w, ASPK, SK, fc2_bn, fc2_b, 256, 1024, 256);
    final_k<<<1024, 256, 0, stream>>>(SK, SV, (float*)d_out);
}